// Round 8
// baseline (143.038 us; speedup 1.0000x reference)
//
#include <hip/hip_runtime.h>
#include <hip/hip_bf16.h>
#include <math.h>

#define B_ 8
#define C_ 256
#define N_ 1024
#define H_ 8
#define DH 96
#define BHN (C_*3*N_)
#define SC 0.10206207261596575f     // 1/sqrt(96)
#define SCL2 0.14722193f            // SC * log2(e): QK scores in log2 domain

typedef _Float16 half8 __attribute__((ext_vector_type(8)));
typedef float f32x4 __attribute__((ext_vector_type(4)));
typedef float f32x16 __attribute__((ext_vector_type(16)));

typedef __attribute__((address_space(1))) void gvoid;
typedef __attribute__((address_space(3))) void lvoid;
__device__ inline void gl_lds16(const _Float16* g, _Float16* l) {
  __builtin_amdgcn_global_load_lds((gvoid*)g, (lvoid*)l, 16, 0, 0);
}

__device__ inline float ex2(float x) { return __builtin_amdgcn_exp2f(x); }

typedef __fp16 fp16x2 __attribute__((ext_vector_type(2)));
union H2U { fp16x2 h2; unsigned u; };
__device__ inline unsigned pkh(float a, float b) {
  H2U x; x.h2 = __builtin_amdgcn_cvt_pkrtz(a, b); return x.u;
}
union PF { half8 v; unsigned u[4]; };

// v_permlane32_swap_b32: a' = [a_lo|b_lo], b' = [a_hi|b_hi]
__device__ inline void plswap(unsigned& a, unsigned& b) {
  asm volatile("v_permlane32_swap_b32 %0, %1" : "+v"(a), "+v"(b));
}

// ---------------------------------------------------------------------------
// Mask -> per-64-key-tile uint64 bitmask: mb[b*16 + t], bit j = key t*64+j pad
// ---------------------------------------------------------------------------
__global__ void mask_bits_kernel(const unsigned* __restrict__ mraw,
                                 unsigned long long* __restrict__ mb) {
  __shared__ int notI, notF;
  if (threadIdx.x == 0) { notI = 0; notF = 0; }
  __syncthreads();
  int li = 0, lf = 0;
  for (int i = threadIdx.x; i < 2048; i += 256) {
    unsigned w = mraw[i];
    if (w > 1u) li = 1;
    if (w != 0u && w != 0x3F800000u) lf = 1;
  }
  if (li) atomicOr(&notI, 1);
  if (lf) atomicOr(&notF, 1);
  __syncthreads();
  const int tid = threadIdx.x;
  if (tid < 128) {
    int base = tid * 64;
    unsigned long long bits = 0;
    if (!notI) {
      for (int j = 0; j < 64; ++j)
        bits |= (unsigned long long)(mraw[base + j] & 1u) << j;
    } else if (!notF) {
      for (int j = 0; j < 64; ++j)
        bits |= (unsigned long long)(mraw[base + j] != 0u ? 1 : 0) << j;
    } else {
      const unsigned char* m8 = (const unsigned char*)mraw;
      for (int j = 0; j < 64; ++j)
        bits |= (unsigned long long)(m8[base + j] ? 1 : 0) << j;
    }
    mb[tid] = bits;
  }
}

// ---------------------------------------------------------------------------
// Weights fp32 -> fp16 [4][256][256]
// ---------------------------------------------------------------------------
__global__ void convw_kernel(const float* __restrict__ Wq,
                             const float* __restrict__ Wk,
                             const float* __restrict__ Wv,
                             const float* __restrict__ Wp,
                             _Float16* __restrict__ Wh) {
  int idx = blockIdx.x * 256 + threadIdx.x;
  int e0 = idx * 8;
  const float* src = (e0 < 65536) ? Wq
                   : (e0 < 131072) ? Wk
                   : (e0 < 196608) ? Wv : Wp;
  int off = e0 & 65535;
  float4 a = *(const float4*)&src[off];
  float4 b = *(const float4*)&src[off + 4];
  _Float16 t[8] = {(_Float16)a.x, (_Float16)a.y, (_Float16)a.z, (_Float16)a.w,
                   (_Float16)b.x, (_Float16)b.y, (_Float16)b.z, (_Float16)b.w};
  *(uint4*)&Wh[e0] = *(uint4*)t;
}

// ---------------------------------------------------------------------------
// x [b][256][3072] fp32 -> XT [b][3072][256] fp16 (n-major)
// ---------------------------------------------------------------------------
__global__ __launch_bounds__(256) void convxt_kernel(
    const float* __restrict__ x, _Float16* __restrict__ XT) {
  __shared__ _Float16 T[64][65];
  const int m0 = blockIdx.x * 64;
  const int c0 = blockIdx.y * 64;
  const int b = blockIdx.z;
  const float* xb = x + (size_t)b * BHN;
  _Float16* ob = XT + (size_t)b * BHN;
  const int t = threadIdx.x;
#pragma unroll
  for (int i = 0; i < 16; ++i) {
    int e = t + i * 256;
    int c = e >> 6, m = e & 63;
    T[m][c] = (_Float16)xb[(size_t)(c0 + c) * 3072 + m0 + m];
  }
  __syncthreads();
#pragma unroll
  for (int i = 0; i < 2; ++i) {
    int e = t + i * 256;
    int m = e >> 3, ch = e & 7;
    _Float16 tmp[8];
#pragma unroll
    for (int j = 0; j < 8; ++j) tmp[j] = T[m][ch * 8 + j];
    *(uint4*)&ob[(size_t)(m0 + m) * 256 + c0 + ch * 8] = *(uint4*)tmp;
  }
}

// ---------------------------------------------------------------------------
// fp16 MFMA GEMM: O = W(256x256) @ X[b](256x3072), X n-major [n][c].
// MODE 0: w=0 -> O0 n-major fp16 *SCL2 (q, log2-domain); w=1 -> O1 n-major
//         fp16 (k); w=2 -> O2 c-major fp16 (v).
// MODE 1: Of c-major fp32 (final out).
// ---------------------------------------------------------------------------
template <int MODE>
__global__ __launch_bounds__(256, 4) void mgemm_kernel(
    const _Float16* __restrict__ Wh, int woff,
    const _Float16* __restrict__ Xn,
    _Float16* __restrict__ O0, _Float16* __restrict__ O1,
    _Float16* __restrict__ O2, float* __restrict__ Of, int nw) {
  const int zz = blockIdx.z;
  const int w = zz % nw;
  const int b = zz / nw;
  const _Float16* Wb = Wh + (size_t)(woff + w) * 65536;
  const _Float16* Bb = Xn + (size_t)b * BHN;
  const int o0 = blockIdx.y * 128;
  const int bn0 = blockIdx.x * 128;

  __shared__ __align__(16) _Float16 Ah[4096];  // [128][32]
  __shared__ __align__(16) _Float16 Bh[4096];  // [128][32]

  const int tid = threadIdx.x;
  const int wave = tid >> 6;
  const int lane = tid & 63;
  const int lg = lane >> 4, ll = lane & 15;
  const int wm = wave >> 1, wn = wave & 1;
  const int r0 = tid >> 2, c4 = tid & 3;

  f32x4 acc[4][4];
#pragma unroll
  for (int mi = 0; mi < 4; ++mi)
#pragma unroll
    for (int ni = 0; ni < 4; ++ni) acc[mi][ni] = (f32x4){0.f, 0.f, 0.f, 0.f};

  for (int k0 = 0; k0 < 256; k0 += 32) {
    gl_lds16(Wb + (size_t)(o0 + r0) * 256 + k0 + c4 * 8, &Ah[wave * 512]);
    gl_lds16(Wb + (size_t)(o0 + 64 + r0) * 256 + k0 + c4 * 8,
             &Ah[2048 + wave * 512]);
    gl_lds16(Bb + (size_t)(bn0 + r0) * 256 + k0 + c4 * 8, &Bh[wave * 512]);
    gl_lds16(Bb + (size_t)(bn0 + 64 + r0) * 256 + k0 + c4 * 8,
             &Bh[2048 + wave * 512]);
    __syncthreads();
    half8 af[4], bf[4];
#pragma unroll
    for (int mi = 0; mi < 4; ++mi)
      af[mi] = *(const half8*)&Ah[(wm * 64 + mi * 16 + ll) * 32 + lg * 8];
#pragma unroll
    for (int ni = 0; ni < 4; ++ni)
      bf[ni] = *(const half8*)&Bh[(wn * 64 + ni * 16 + ll) * 32 + lg * 8];
#pragma unroll
    for (int mi = 0; mi < 4; ++mi)
#pragma unroll
      for (int ni = 0; ni < 4; ++ni)
        acc[mi][ni] = __builtin_amdgcn_mfma_f32_16x16x32_f16(
            af[mi], bf[ni], acc[mi][ni], 0, 0, 0);
    __syncthreads();
  }

#pragma unroll
  for (int mi = 0; mi < 4; ++mi) {
#pragma unroll
    for (int ni = 0; ni < 4; ++ni) {
      int o = o0 + wm * 64 + mi * 16 + lg * 4;
      int n = bn0 + wn * 64 + ni * 16 + ll;
      if constexpr (MODE == 1) {
        float* Ofb = Of + (size_t)b * BHN;
#pragma unroll
        for (int r = 0; r < 4; ++r)
          Ofb[(size_t)(o + r) * 3072 + n] = acc[mi][ni][r];
      } else {
        if (w == 2) {
          _Float16* Oc = O2 + (size_t)b * BHN;
#pragma unroll
          for (int r = 0; r < 4; ++r)
            Oc[(size_t)(o + r) * 3072 + n] = (_Float16)acc[mi][ni][r];
        } else {
          _Float16* On = ((w == 0) ? O0 : O1) + (size_t)b * BHN;
          float qs = (w == 0) ? SCL2 : 1.0f;
          _Float16 t4[4];
#pragma unroll
          for (int r = 0; r < 4; ++r) t4[r] = (_Float16)(acc[mi][ni][r] * qs);
          *(uint2*)&On[(size_t)n * 256 + o] = *(uint2*)t4;
        }
      }
    }
  }
}

// ---------------------------------------------------------------------------
// Flash attention, 32x32 swapped-QK^T — LDS-FREE, BARRIER-FREE.
// Every MFMA fragment is 16 contiguous bytes in global memory:
//   Q/K (n-major):  frag(ks,hi) at [dd*1024 + row][h*32 + i0],
//                   dd=(2ks+hi)>>2, i0=((2ks+hi)&3)*8
//   V (c-major):    frag(kt,hi,dt) at row c=h*32+lq, col dt*1024+m0+(kt*2+hi)*8
// Softmax in exp2 domain (q pre-scaled by SC*log2e). Defer-max THR=12.
// C/D map (HW-verified): col=lane&31, row=(r&3)+8*(r>>2)+4*(lane>>5).
// ---------------------------------------------------------------------------
__global__ __launch_bounds__(256, 2) void attn_kernel(
    const _Float16* __restrict__ qh, const _Float16* __restrict__ kh,
    const _Float16* __restrict__ vh,
    const unsigned long long* __restrict__ mbits,
    _Float16* __restrict__ yT) {
  const int gid = blockIdx.x;
  const int bh = gid & 63;   // XCD = gid%8 = h: per-XCD K/V set 3.1MB, L2-fit
  const int qt = gid >> 6;
  const int b = bh >> 3, h = bh & 7;
  const int n0 = qt * 128;

  const int tid = threadIdx.x;
  const int lane = tid & 63;
  const int wave = tid >> 6;
  const int hi = lane >> 5;
  const int lq = lane & 31;
  const int wq0 = wave * 32;

  const _Float16* qb = qh + (size_t)b * BHN;
  const _Float16* kb = kh + (size_t)b * BHN;
  const _Float16* vb = vh + (size_t)b * BHN;

  // ---- Q fragments direct from global ----
  half8 qf[6];
#pragma unroll
  for (int ks = 0; ks < 6; ++ks) {
    int pp = 2 * ks + hi;
    int dd = pp >> 2, i0 = (pp & 3) * 8;
    qf[ks] = *(const half8*)(qb +
        (size_t)(dd * 1024 + n0 + wq0 + lq) * 256 + h * 32 + i0);
  }

  const _Float16* vrow = vb + (size_t)(h * 32 + lq) * 3072;  // V row base

  float M = 0.f, Lh = 0.f;
  f32x16 yacc[3];
#pragma unroll
  for (int dt = 0; dt < 3; ++dt)
#pragma unroll
    for (int r = 0; r < 16; ++r) yacc[dt][r] = 0.f;

  for (int t = 0; t < 16; ++t) {
    const int m0 = t * 64;
    // ---- K fragments (12 x dwordx4) ----
    half8 kf[6][2];
#pragma unroll
    for (int ks = 0; ks < 6; ++ks) {
      int pp = 2 * ks + hi;
      int dd = pp >> 2, i0 = (pp & 3) * 8;
      const _Float16* base =
          kb + (size_t)(dd * 1024 + m0 + lq) * 256 + h * 32 + i0;
      kf[ks][0] = *(const half8*)base;
      kf[ks][1] = *(const half8*)(base + 32 * 256);
    }
    // ---- V fragments (12 x dwordx4), issued early to hide latency ----
    half8 vf[4][3];
#pragma unroll
    for (int kt = 0; kt < 4; ++kt)
#pragma unroll
      for (int dt = 0; dt < 3; ++dt)
        vf[kt][dt] =
            *(const half8*)(vrow + dt * 1024 + m0 + (kt * 2 + hi) * 8);

    const unsigned long long m64 = mbits[b * 16 + t];

    // ---- S = K.Q^T (swapped): rows=keys, cols=q ----
    f32x16 s[2];
#pragma unroll
    for (int r = 0; r < 16; ++r) { s[0][r] = 0.f; s[1][r] = 0.f; }
    __builtin_amdgcn_s_setprio(1);
#pragma unroll
    for (int ks = 0; ks < 6; ++ks) {
      s[0] = __builtin_amdgcn_mfma_f32_32x32x16_f16(kf[ks][0], qf[ks], s[0],
                                                    0, 0, 0);
      s[1] = __builtin_amdgcn_mfma_f32_32x32x16_f16(kf[ks][1], qf[ks], s[1],
                                                    0, 0, 0);
    }
    __builtin_amdgcn_s_setprio(0);

    // ---- mask + local max ----
    float mx = -1e30f;
#pragma unroll
    for (int nt = 0; nt < 2; ++nt) {
      unsigned wm = (unsigned)(m64 >> (nt * 32 + 4 * hi));
#pragma unroll
      for (int r = 0; r < 16; ++r) {
        float sv = s[nt][r];
        sv = ((wm >> ((r & 3) + 8 * (r >> 2))) & 1u) ? -1e30f : sv;
        s[nt][r] = sv;
        mx = fmaxf(mx, sv);
      }
    }
    // ---- deferred max (THR=12 in log2 domain: P <= 2^12) ----
    if (__any(mx > M + 12.f)) {
      float mx2 = fmaxf(mx, __shfl_xor(mx, 32));
      float newM = fmaxf(M, mx2);
      float corr = ex2(M - newM);
      M = newM;
      Lh *= corr;
#pragma unroll
      for (int dt = 0; dt < 3; ++dt)
#pragma unroll
        for (int r = 0; r < 16; ++r) yacc[dt][r] *= corr;
    }
    float psum = 0.f;
#pragma unroll
    for (int nt = 0; nt < 2; ++nt)
#pragma unroll
      for (int r = 0; r < 16; ++r) {
        float p = ex2(s[nt][r] - M);
        s[nt][r] = p;
        psum += p;
      }
    Lh += psum;

    // ---- P -> fp16 B-frags via permlane32_swap, PV accumulate ----
#pragma unroll
    for (int nt = 0; nt < 2; ++nt) {
#pragma unroll
      for (int hf = 0; hf < 2; ++hf) {
        const int bs = hf * 8;
        unsigned A0 = pkh(s[nt][bs + 0], s[nt][bs + 1]);
        unsigned A1 = pkh(s[nt][bs + 2], s[nt][bs + 3]);
        unsigned B0 = pkh(s[nt][bs + 4], s[nt][bs + 5]);
        unsigned B1 = pkh(s[nt][bs + 6], s[nt][bs + 7]);
        plswap(A0, B0);
        plswap(A1, B1);
        PF pf;
        pf.u[0] = A0;
        pf.u[1] = A1;
        pf.u[2] = B0;
        pf.u[3] = B1;
        const int kt = nt * 2 + hf;
        __builtin_amdgcn_s_setprio(1);
#pragma unroll
        for (int dt = 0; dt < 3; ++dt)
          yacc[dt] = __builtin_amdgcn_mfma_f32_32x32x16_f16(
              vf[kt][dt], pf.v, yacc[dt], 0, 0, 0);
        __builtin_amdgcn_s_setprio(0);
      }
    }
  }

  // ---- epilogue: direct n-major stores (4-contig dperm groups = 8B) ----
  float L = Lh + __shfl_xor(Lh, 32);
  float inv = (L > 0.f) ? 1.f / L : 0.f;
  _Float16* yb = yT + (size_t)b * BHN;
#pragma unroll
  for (int dt = 0; dt < 3; ++dt) {
    _Float16* rowp =
        yb + (size_t)(dt * 1024 + n0 + wq0 + lq) * 256 + h * 32 + hi * 4;
#pragma unroll
    for (int g = 0; g < 4; ++g) {
      _Float16 t4[4];
#pragma unroll
      for (int j = 0; j < 4; ++j)
        t4[j] = (_Float16)(yacc[dt][g * 4 + j] * inv);
      *(uint2*)(rowp + g * 8) = *(uint2*)t4;
    }
  }
}

// ---------------------------------------------------------------------------
extern "C" void kernel_launch(void* const* d_in, const int* in_sizes, int n_in,
                              void* d_out, int out_size, void* d_ws,
                              size_t ws_size, hipStream_t stream) {
  const float* x = (const float*)d_in[0];
  const float* Wq = (const float*)d_in[1];
  const float* Wk = (const float*)d_in[2];
  const float* Wv = (const float*)d_in[3];
  const float* Wp = (const float*)d_in[4];
  const unsigned* mask = (const unsigned*)d_in[5];
  float* out = (float*)d_out;

  _Float16* Wh = (_Float16*)d_ws;                   // 0.5 MB
  _Float16* XT = Wh + 4 * 65536;                    // 12.6 MB n-major
  _Float16* qh = XT + (size_t)B_ * BHN;             // 12.6 MB n-major (scaled)
  _Float16* kh = qh + (size_t)B_ * BHN;             // 12.6 MB n-major
  _Float16* vh = kh + (size_t)B_ * BHN;             // 12.6 MB c-major
  _Float16* yT = vh + (size_t)B_ * BHN;             // 12.6 MB n-major
  unsigned long long* mb = (unsigned long long*)(yT + (size_t)B_ * BHN);

  mask_bits_kernel<<<1, 256, 0, stream>>>(mask, mb);
  convw_kernel<<<128, 256, 0, stream>>>(Wq, Wk, Wv, Wp, Wh);
  convxt_kernel<<<dim3(48, 4, B_), 256, 0, stream>>>(x, XT);

  dim3 g1(24, 2, B_ * 3);
  mgemm_kernel<0><<<g1, 256, 0, stream>>>(Wh, 0, XT, qh, kh, vh, nullptr, 3);

  attn_kernel<<<dim3(512), 256, 0, stream>>>(qh, kh, vh, mb, yT);

  dim3 g3(24, 2, B_);
  mgemm_kernel<1><<<g3, 256, 0, stream>>>(Wh, 3, yT, nullptr, nullptr, nullptr,
                                          out, 1);
}

// Round 9
// 93.828 us; speedup vs baseline: 1.5245x; 1.5245x over previous
//
#include <hip/hip_runtime.h>
#include <hip/hip_bf16.h>
#include <math.h>

#define B_ 8
#define C_ 256
#define N_ 1024
#define H_ 8
#define DH 96
#define BHN (C_*3*N_)
#define SC 0.10206207261596575f     // 1/sqrt(96)
#define SCL2 0.14722193f            // SC * log2(e): QK scores in log2 domain

typedef _Float16 half8 __attribute__((ext_vector_type(8)));
typedef float f32x4 __attribute__((ext_vector_type(4)));
typedef float f32x16 __attribute__((ext_vector_type(16)));

typedef __attribute__((address_space(1))) void gvoid;
typedef __attribute__((address_space(3))) void lvoid;
__device__ inline void gl_lds16(const _Float16* g, _Float16* l) {
  __builtin_amdgcn_global_load_lds((gvoid*)g, (lvoid*)l, 16, 0, 0);
}

__device__ inline float ex2(float x) { return __builtin_amdgcn_exp2f(x); }

typedef __fp16 fp16x2 __attribute__((ext_vector_type(2)));
union H2U { fp16x2 h2; unsigned u; };
__device__ inline unsigned pkh(float a, float b) {
  H2U x; x.h2 = __builtin_amdgcn_cvt_pkrtz(a, b); return x.u;
}
union PF { half8 v; unsigned u[4]; };

// v_permlane32_swap_b32: a' = [a_lo|b_lo], b' = [a_hi|b_hi]
__device__ inline void plswap(unsigned& a, unsigned& b) {
  asm volatile("v_permlane32_swap_b32 %0, %1" : "+v"(a), "+v"(b));
}

// ---------------------------------------------------------------------------
// Mask -> per-64-key-tile uint64 bitmask
// ---------------------------------------------------------------------------
__global__ void mask_bits_kernel(const unsigned* __restrict__ mraw,
                                 unsigned long long* __restrict__ mb) {
  __shared__ int notI, notF;
  if (threadIdx.x == 0) { notI = 0; notF = 0; }
  __syncthreads();
  int li = 0, lf = 0;
  for (int i = threadIdx.x; i < 2048; i += 256) {
    unsigned w = mraw[i];
    if (w > 1u) li = 1;
    if (w != 0u && w != 0x3F800000u) lf = 1;
  }
  if (li) atomicOr(&notI, 1);
  if (lf) atomicOr(&notF, 1);
  __syncthreads();
  const int tid = threadIdx.x;
  if (tid < 128) {
    int base = tid * 64;
    unsigned long long bits = 0;
    if (!notI) {
      for (int j = 0; j < 64; ++j)
        bits |= (unsigned long long)(mraw[base + j] & 1u) << j;
    } else if (!notF) {
      for (int j = 0; j < 64; ++j)
        bits |= (unsigned long long)(mraw[base + j] != 0u ? 1 : 0) << j;
    } else {
      const unsigned char* m8 = (const unsigned char*)mraw;
      for (int j = 0; j < 64; ++j)
        bits |= (unsigned long long)(m8[base + j] ? 1 : 0) << j;
    }
    mb[tid] = bits;
  }
}

// ---------------------------------------------------------------------------
// Weights fp32 -> fp16 [4][256][256]
// ---------------------------------------------------------------------------
__global__ void convw_kernel(const float* __restrict__ Wq,
                             const float* __restrict__ Wk,
                             const float* __restrict__ Wv,
                             const float* __restrict__ Wp,
                             _Float16* __restrict__ Wh) {
  int idx = blockIdx.x * 256 + threadIdx.x;
  int e0 = idx * 8;
  const float* src = (e0 < 65536) ? Wq
                   : (e0 < 131072) ? Wk
                   : (e0 < 196608) ? Wv : Wp;
  int off = e0 & 65535;
  float4 a = *(const float4*)&src[off];
  float4 b = *(const float4*)&src[off + 4];
  _Float16 t[8] = {(_Float16)a.x, (_Float16)a.y, (_Float16)a.z, (_Float16)a.w,
                   (_Float16)b.x, (_Float16)b.y, (_Float16)b.z, (_Float16)b.w};
  *(uint4*)&Wh[e0] = *(uint4*)t;
}

// ---------------------------------------------------------------------------
// x [b][256][3072] fp32 -> XT [b][3072][256] fp16 (n-major)
// ---------------------------------------------------------------------------
__global__ __launch_bounds__(256) void convxt_kernel(
    const float* __restrict__ x, _Float16* __restrict__ XT) {
  __shared__ _Float16 T[64][65];
  const int m0 = blockIdx.x * 64;
  const int c0 = blockIdx.y * 64;
  const int b = blockIdx.z;
  const float* xb = x + (size_t)b * BHN;
  _Float16* ob = XT + (size_t)b * BHN;
  const int t = threadIdx.x;
#pragma unroll
  for (int i = 0; i < 16; ++i) {
    int e = t + i * 256;
    int c = e >> 6, m = e & 63;
    T[m][c] = (_Float16)xb[(size_t)(c0 + c) * 3072 + m0 + m];
  }
  __syncthreads();
#pragma unroll
  for (int i = 0; i < 2; ++i) {
    int e = t + i * 256;
    int m = e >> 3, ch = e & 7;
    _Float16 tmp[8];
#pragma unroll
    for (int j = 0; j < 8; ++j) tmp[j] = T[m][ch * 8 + j];
    *(uint4*)&ob[(size_t)(m0 + m) * 256 + c0 + ch * 8] = *(uint4*)tmp;
  }
}

// ---------------------------------------------------------------------------
// fp16 MFMA GEMM: O = W(256x256) @ X[b](256x3072), X n-major [n][c].
// MODE 0: scatter into packed fragment layouts for attention:
//   w=0 Qp[bh][qt32][ks6][ql32][hi2][8]  (scaled by SCL2)
//   w=1 Kp[bh][t16][ks6][kk64][hi2][8]
//   w=2 Vp[bh][t16][kt4][dt3][lq32][hi2][8]
// MODE 1: Of c-major fp32 (final out).
// ---------------------------------------------------------------------------
template <int MODE>
__global__ __launch_bounds__(256, 4) void mgemm_kernel(
    const _Float16* __restrict__ Wh, int woff,
    const _Float16* __restrict__ Xn,
    _Float16* __restrict__ O0, _Float16* __restrict__ O1,
    _Float16* __restrict__ O2, float* __restrict__ Of, int nw) {
  const int zz = blockIdx.z;
  const int w = zz % nw;
  const int b = zz / nw;
  const _Float16* Wb = Wh + (size_t)(woff + w) * 65536;
  const _Float16* Bb = Xn + (size_t)b * BHN;
  const int o0 = blockIdx.y * 128;
  const int bn0 = blockIdx.x * 128;

  __shared__ __align__(16) _Float16 Ah[4096];  // [128][32]
  __shared__ __align__(16) _Float16 Bh[4096];  // [128][32]

  const int tid = threadIdx.x;
  const int wave = tid >> 6;
  const int lane = tid & 63;
  const int lg = lane >> 4, ll = lane & 15;
  const int wm = wave >> 1, wn = wave & 1;
  const int r0 = tid >> 2, c4 = tid & 3;

  f32x4 acc[4][4];
#pragma unroll
  for (int mi = 0; mi < 4; ++mi)
#pragma unroll
    for (int ni = 0; ni < 4; ++ni) acc[mi][ni] = (f32x4){0.f, 0.f, 0.f, 0.f};

  for (int k0 = 0; k0 < 256; k0 += 32) {
    gl_lds16(Wb + (size_t)(o0 + r0) * 256 + k0 + c4 * 8, &Ah[wave * 512]);
    gl_lds16(Wb + (size_t)(o0 + 64 + r0) * 256 + k0 + c4 * 8,
             &Ah[2048 + wave * 512]);
    gl_lds16(Bb + (size_t)(bn0 + r0) * 256 + k0 + c4 * 8, &Bh[wave * 512]);
    gl_lds16(Bb + (size_t)(bn0 + 64 + r0) * 256 + k0 + c4 * 8,
             &Bh[2048 + wave * 512]);
    __syncthreads();
    half8 af[4], bf[4];
#pragma unroll
    for (int mi = 0; mi < 4; ++mi)
      af[mi] = *(const half8*)&Ah[(wm * 64 + mi * 16 + ll) * 32 + lg * 8];
#pragma unroll
    for (int ni = 0; ni < 4; ++ni)
      bf[ni] = *(const half8*)&Bh[(wn * 64 + ni * 16 + ll) * 32 + lg * 8];
#pragma unroll
    for (int mi = 0; mi < 4; ++mi)
#pragma unroll
      for (int ni = 0; ni < 4; ++ni)
        acc[mi][ni] = __builtin_amdgcn_mfma_f32_16x16x32_f16(
            af[mi], bf[ni], acc[mi][ni], 0, 0, 0);
    __syncthreads();
  }

#pragma unroll
  for (int mi = 0; mi < 4; ++mi) {
#pragma unroll
    for (int ni = 0; ni < 4; ++ni) {
      int o = o0 + wm * 64 + mi * 16 + lg * 4;   // channel (4 consecutive via r)
      int mcol = bn0 + wn * 64 + ni * 16 + ll;   // dd*1024 + token
      if constexpr (MODE == 1) {
        float* Ofb = Of + (size_t)b * BHN;
#pragma unroll
        for (int r = 0; r < 4; ++r)
          Ofb[(size_t)(o + r) * 3072 + mcol] = acc[mi][ni][r];
      } else {
        const int h = o >> 5, i = o & 31;
        const int dd = mcol >> 10, tok = mcol & 1023;
        const size_t bh8 = (size_t)(b * 8 + h);
        if (w == 2) {
          // Vp[bh][t][kt][dt=dd][lq=i(+r)][hi2][e]
          int tt = tok >> 6, kk = tok & 63;
          int kt = kk >> 4, hi2 = (kk >> 3) & 1, e = kk & 7;
          size_t base = ((((bh8 * 16 + tt) * 4 + kt) * 3 + dd) * 512) +
                        (size_t)i * 16 + hi2 * 8 + e;
#pragma unroll
          for (int r = 0; r < 4; ++r)
            O2[base + r * 16] = (_Float16)acc[mi][ni][r];
        } else {
          int dperm = dd * 32 + i;
          int pp = dperm >> 3, j0 = i & 7;
          int ks = pp >> 1, hif = pp & 1;
          float qs = (w == 0) ? SCL2 : 1.0f;
          _Float16 t4[4];
#pragma unroll
          for (int r = 0; r < 4; ++r) t4[r] = (_Float16)(acc[mi][ni][r] * qs);
          size_t idx;
          if (w == 0) {
            // Qp[bh][qt32][ks][ql][hi][j]
            idx = ((bh8 * 32 + (tok >> 5)) * 6 + ks) * 512 +
                  (size_t)(tok & 31) * 16 + hif * 8 + j0;
            *(uint2*)&O0[idx] = *(uint2*)t4;
          } else {
            // Kp[bh][t][ks][kk][hi][j]
            idx = ((bh8 * 16 + (tok >> 6)) * 6 + ks) * 1024 +
                  (size_t)(tok & 63) * 16 + hif * 8 + j0;
            *(uint2*)&O1[idx] = *(uint2*)t4;
          }
        }
      }
    }
  }
}

// ---------------------------------------------------------------------------
// Flash attention, 32x32 swapped-QK^T — LDS-free, barrier-free, with packed
// fragment-major q/k/v so every fragment load is 64 lanes x 16B CONTIGUOUS
// (2KB dense; K+V tile = 12KB, L1-resident, shared by the block's 4 waves).
// Software pipeline: V(t) loads issue at tile start (consumed in PV ~700cy
// later); K(t+1) reloads issue right after QK^T(t) (covered by softmax+PV).
// Softmax in exp2 domain (q pre-scaled by SC*log2e), defer-max THR=12.
// C/D map (HW-verified): col=lane&31, row=(r&3)+8*(r>>2)+4*(lane>>5).
// ---------------------------------------------------------------------------
__global__ __launch_bounds__(256, 2) void attn_kernel(
    const _Float16* __restrict__ Qp, const _Float16* __restrict__ Kp,
    const _Float16* __restrict__ Vp,
    const unsigned long long* __restrict__ mbits,
    _Float16* __restrict__ yT) {
  const int gid = blockIdx.x;
  const int bh = gid & 63;   // XCD = gid%8 = h: per-XCD K/V set L2-resident
  const int qt = gid >> 6;
  const int b = bh >> 3, h = bh & 7;
  const int n0 = qt * 128;

  const int tid = threadIdx.x;
  const int lane = tid & 63;
  const int wave = tid >> 6;
  const int hi = lane >> 5;
  const int lq = lane & 31;
  const int wq0 = wave * 32;

  const size_t bh8 = (size_t)(b * 8 + h);
  const int lo16 = lq * 16 + hi * 8;   // per-lane offset within a 2KB frag blk

  // ---- Q fragments (contiguous 1KB per frag) ----
  const _Float16* Qb = Qp + (bh8 * 32 + (qt * 4 + wave)) * 6 * 512 + lo16;
  half8 qf[6];
#pragma unroll
  for (int ks = 0; ks < 6; ++ks) qf[ks] = *(const half8*)(Qb + ks * 512);

  const _Float16* Kh = Kp + bh8 * 98304 + lo16;
  const _Float16* Vh = Vp + bh8 * 98304 + lo16;

  half8 kf[6][2];
  auto loadK = [&](int t) {
    const _Float16* Kt = Kh + t * 6144;
#pragma unroll
    for (int ks = 0; ks < 6; ++ks) {
      kf[ks][0] = *(const half8*)(Kt + ks * 1024);
      kf[ks][1] = *(const half8*)(Kt + ks * 1024 + 512);
    }
  };
  loadK(0);

  float M = 0.f, Lh = 0.f;
  f32x16 yacc[3];
#pragma unroll
  for (int dt = 0; dt < 3; ++dt)
#pragma unroll
    for (int r = 0; r < 16; ++r) yacc[dt][r] = 0.f;

  for (int t = 0; t < 16; ++t) {
    // ---- V fragments for this tile (12 x 2KB-dense loads), issued early ----
    const _Float16* Vt = Vh + t * 6144;
    half8 vf[4][3];
#pragma unroll
    for (int kt = 0; kt < 4; ++kt)
#pragma unroll
      for (int dt = 0; dt < 3; ++dt)
        vf[kt][dt] = *(const half8*)(Vt + (kt * 3 + dt) * 512);

    const unsigned long long m64 = mbits[b * 16 + t];

    // ---- S = K.Q^T (swapped): rows=keys, cols=q ----
    f32x16 s[2];
#pragma unroll
    for (int r = 0; r < 16; ++r) { s[0][r] = 0.f; s[1][r] = 0.f; }
    __builtin_amdgcn_s_setprio(1);
#pragma unroll
    for (int ks = 0; ks < 6; ++ks) {
      s[0] = __builtin_amdgcn_mfma_f32_32x32x16_f16(kf[ks][0], qf[ks], s[0],
                                                    0, 0, 0);
      s[1] = __builtin_amdgcn_mfma_f32_32x32x16_f16(kf[ks][1], qf[ks], s[1],
                                                    0, 0, 0);
    }
    __builtin_amdgcn_s_setprio(0);

    // ---- K reload for next tile (WAR on kf; covered by softmax+PV) ----
    if (t + 1 < 16) loadK(t + 1);

    // ---- mask + local max ----
    float mx = -1e30f;
#pragma unroll
    for (int nt = 0; nt < 2; ++nt) {
      unsigned wm = (unsigned)(m64 >> (nt * 32 + 4 * hi));
#pragma unroll
      for (int r = 0; r < 16; ++r) {
        float sv = s[nt][r];
        sv = ((wm >> ((r & 3) + 8 * (r >> 2))) & 1u) ? -1e30f : sv;
        s[nt][r] = sv;
        mx = fmaxf(mx, sv);
      }
    }
    // ---- deferred max (THR=12 in log2 domain: P <= 2^12) ----
    if (__any(mx > M + 12.f)) {
      float mx2 = fmaxf(mx, __shfl_xor(mx, 32));
      float newM = fmaxf(M, mx2);
      float corr = ex2(M - newM);
      M = newM;
      Lh *= corr;
#pragma unroll
      for (int dt = 0; dt < 3; ++dt)
#pragma unroll
        for (int r = 0; r < 16; ++r) yacc[dt][r] *= corr;
    }
    float psum = 0.f;
#pragma unroll
    for (int nt = 0; nt < 2; ++nt)
#pragma unroll
      for (int r = 0; r < 16; ++r) {
        float p = ex2(s[nt][r] - M);
        s[nt][r] = p;
        psum += p;
      }
    Lh += psum;

    // ---- P -> fp16 B-frags via permlane32_swap, PV accumulate ----
#pragma unroll
    for (int nt = 0; nt < 2; ++nt) {
#pragma unroll
      for (int hf = 0; hf < 2; ++hf) {
        const int bs = hf * 8;
        unsigned A0 = pkh(s[nt][bs + 0], s[nt][bs + 1]);
        unsigned A1 = pkh(s[nt][bs + 2], s[nt][bs + 3]);
        unsigned B0 = pkh(s[nt][bs + 4], s[nt][bs + 5]);
        unsigned B1 = pkh(s[nt][bs + 6], s[nt][bs + 7]);
        plswap(A0, B0);
        plswap(A1, B1);
        PF pf;
        pf.u[0] = A0;
        pf.u[1] = A1;
        pf.u[2] = B0;
        pf.u[3] = B1;
        const int kt = nt * 2 + hf;
        __builtin_amdgcn_s_setprio(1);
#pragma unroll
        for (int dt = 0; dt < 3; ++dt)
          yacc[dt] = __builtin_amdgcn_mfma_f32_32x32x16_f16(
              vf[kt][dt], pf.v, yacc[dt], 0, 0, 0);
        __builtin_amdgcn_s_setprio(0);
      }
    }
  }

  // ---- epilogue: direct n-major stores ----
  float L = Lh + __shfl_xor(Lh, 32);
  float inv = (L > 0.f) ? 1.f / L : 0.f;
  _Float16* yb = yT + (size_t)b * BHN;
#pragma unroll
  for (int dt = 0; dt < 3; ++dt) {
    _Float16* rowp =
        yb + (size_t)(dt * 1024 + n0 + wq0 + lq) * 256 + h * 32 + hi * 4;
#pragma unroll
    for (int g = 0; g < 4; ++g) {
      _Float16 t4[4];
#pragma unroll
      for (int j = 0; j < 4; ++j)
        t4[j] = (_Float16)(yacc[dt][g * 4 + j] * inv);
      *(uint2*)(rowp + g * 8) = *(uint2*)t4;
    }
  }
}

// ---------------------------------------------------------------------------
extern "C" void kernel_launch(void* const* d_in, const int* in_sizes, int n_in,
                              void* d_out, int out_size, void* d_ws,
                              size_t ws_size, hipStream_t stream) {
  const float* x = (const float*)d_in[0];
  const float* Wq = (const float*)d_in[1];
  const float* Wk = (const float*)d_in[2];
  const float* Wv = (const float*)d_in[3];
  const float* Wp = (const float*)d_in[4];
  const unsigned* mask = (const unsigned*)d_in[5];
  float* out = (float*)d_out;

  _Float16* Wh = (_Float16*)d_ws;                   // 0.5 MB
  _Float16* XT = Wh + 4 * 65536;                    // 12.6 MB n-major
  _Float16* Qp = XT + (size_t)B_ * BHN;             // 12.6 MB packed frags
  _Float16* Kp = Qp + (size_t)B_ * BHN;             // 12.6 MB packed frags
  _Float16* Vp = Kp + (size_t)B_ * BHN;             // 12.6 MB packed frags
  _Float16* yT = Vp + (size_t)B_ * BHN;             // 12.6 MB n-major
  unsigned long long* mb = (unsigned long long*)(yT + (size_t)B_ * BHN);

  mask_bits_kernel<<<1, 256, 0, stream>>>(mask, mb);
  convw_kernel<<<128, 256, 0, stream>>>(Wq, Wk, Wv, Wp, Wh);
  convxt_kernel<<<dim3(48, 4, B_), 256, 0, stream>>>(x, XT);

  dim3 g1(24, 2, B_ * 3);
  mgemm_kernel<0><<<g1, 256, 0, stream>>>(Wh, 0, XT, Qp, Kp, Vp, nullptr, 3);

  attn_kernel<<<dim3(512), 256, 0, stream>>>(Qp, Kp, Vp, mb, yT);

  dim3 g3(24, 2, B_);
  mgemm_kernel<1><<<g3, 256, 0, stream>>>(Wh, 3, yT, nullptr, nullptr, nullptr,
                                          out, 1);
}

// Round 10
// 91.109 us; speedup vs baseline: 1.5700x; 1.0298x over previous
//
#include <hip/hip_runtime.h>
#include <hip/hip_bf16.h>
#include <math.h>

#define B_ 8
#define C_ 256
#define N_ 1024
#define H_ 8
#define DH 96
#define BHN (C_*3*N_)
#define SC 0.10206207261596575f     // 1/sqrt(96)
#define SCL2 0.14722193f            // SC * log2(e): QK scores in log2 domain

typedef _Float16 half8 __attribute__((ext_vector_type(8)));
typedef float f32x4 __attribute__((ext_vector_type(4)));
typedef float f32x16 __attribute__((ext_vector_type(16)));

typedef __attribute__((address_space(1))) void gvoid;
typedef __attribute__((address_space(3))) void lvoid;
__device__ inline void gl_lds16(const _Float16* g, _Float16* l) {
  __builtin_amdgcn_global_load_lds((gvoid*)g, (lvoid*)l, 16, 0, 0);
}

__device__ inline float ex2(float x) { return __builtin_amdgcn_exp2f(x); }

typedef __fp16 fp16x2 __attribute__((ext_vector_type(2)));
union H2U { fp16x2 h2; unsigned u; };
__device__ inline unsigned pkh(float a, float b) {
  H2U x; x.h2 = __builtin_amdgcn_cvt_pkrtz(a, b); return x.u;
}
union PF { half8 v; unsigned u[4]; };

// v_permlane32_swap_b32: a' = [a_lo|b_lo], b' = [a_hi|b_hi]
__device__ inline void plswap(unsigned& a, unsigned& b) {
  asm volatile("v_permlane32_swap_b32 %0, %1" : "+v"(a), "+v"(b));
}

// ---------------------------------------------------------------------------
// Weights fp32 -> fp16 [4][256][256]; block 0 additionally builds the mask
// bitmask (fused to save one dispatch).
// ---------------------------------------------------------------------------
__global__ void convw_kernel(const float* __restrict__ Wq,
                             const float* __restrict__ Wk,
                             const float* __restrict__ Wv,
                             const float* __restrict__ Wp,
                             _Float16* __restrict__ Wh,
                             const unsigned* __restrict__ mraw,
                             unsigned long long* __restrict__ mb) {
  int idx = blockIdx.x * 256 + threadIdx.x;
  int e0 = idx * 8;
  const float* src = (e0 < 65536) ? Wq
                   : (e0 < 131072) ? Wk
                   : (e0 < 196608) ? Wv : Wp;
  int off = e0 & 65535;
  float4 a = *(const float4*)&src[off];
  float4 b = *(const float4*)&src[off + 4];
  _Float16 t[8] = {(_Float16)a.x, (_Float16)a.y, (_Float16)a.z, (_Float16)a.w,
                   (_Float16)b.x, (_Float16)b.y, (_Float16)b.z, (_Float16)b.w};
  *(uint4*)&Wh[e0] = *(uint4*)t;

  if (blockIdx.x == 0) {
    __shared__ int notI, notF;
    if (threadIdx.x == 0) { notI = 0; notF = 0; }
    __syncthreads();
    int li = 0, lf = 0;
    for (int i = threadIdx.x; i < 2048; i += 256) {
      unsigned w = mraw[i];
      if (w > 1u) li = 1;
      if (w != 0u && w != 0x3F800000u) lf = 1;
    }
    if (li) atomicOr(&notI, 1);
    if (lf) atomicOr(&notF, 1);
    __syncthreads();
    const int tid = threadIdx.x;
    if (tid < 128) {
      int base = tid * 64;
      unsigned long long bits = 0;
      if (!notI) {
        for (int j = 0; j < 64; ++j)
          bits |= (unsigned long long)(mraw[base + j] & 1u) << j;
      } else if (!notF) {
        for (int j = 0; j < 64; ++j)
          bits |= (unsigned long long)(mraw[base + j] != 0u ? 1 : 0) << j;
      } else {
        const unsigned char* m8 = (const unsigned char*)mraw;
        for (int j = 0; j < 64; ++j)
          bits |= (unsigned long long)(m8[base + j] ? 1 : 0) << j;
      }
      mb[tid] = bits;
    }
  }
}

// ---------------------------------------------------------------------------
// x [b][256][3072] fp32 -> XT [b][3072][256] fp16 (n-major)
// ---------------------------------------------------------------------------
__global__ __launch_bounds__(256) void convxt_kernel(
    const float* __restrict__ x, _Float16* __restrict__ XT) {
  __shared__ _Float16 T[64][65];
  const int m0 = blockIdx.x * 64;
  const int c0 = blockIdx.y * 64;
  const int b = blockIdx.z;
  const float* xb = x + (size_t)b * BHN;
  _Float16* ob = XT + (size_t)b * BHN;
  const int t = threadIdx.x;
#pragma unroll
  for (int i = 0; i < 16; ++i) {
    int e = t + i * 256;
    int c = e >> 6, m = e & 63;
    T[m][c] = (_Float16)xb[(size_t)(c0 + c) * 3072 + m0 + m];
  }
  __syncthreads();
#pragma unroll
  for (int i = 0; i < 2; ++i) {
    int e = t + i * 256;
    int m = e >> 3, ch = e & 7;
    _Float16 tmp[8];
#pragma unroll
    for (int j = 0; j < 8; ++j) tmp[j] = T[m][ch * 8 + j];
    *(uint4*)&ob[(size_t)(m0 + m) * 256 + c0 + ch * 8] = *(uint4*)tmp;
  }
}

// ---------------------------------------------------------------------------
// fp16 MFMA GEMM: O = W(256x256) @ X[b](256x3072), X n-major [n][c].
// MODE 0: scatter into packed fragment layouts for attention:
//   w=0 Qp[bh][qt32][ks6][ql32][hi2][8]  (scaled by SCL2)
//   w=1 Kp[bh][t16][ks6][kk64][hi2][8]
//   w=2 Vp[bh][t16][kt4][dt3][lq32][hi2][8]
// MODE 1: Of c-major fp32 (final out).
// ---------------------------------------------------------------------------
template <int MODE>
__global__ __launch_bounds__(256, 4) void mgemm_kernel(
    const _Float16* __restrict__ Wh, int woff,
    const _Float16* __restrict__ Xn,
    _Float16* __restrict__ O0, _Float16* __restrict__ O1,
    _Float16* __restrict__ O2, float* __restrict__ Of, int nw) {
  const int zz = blockIdx.z;
  const int w = zz % nw;
  const int b = zz / nw;
  const _Float16* Wb = Wh + (size_t)(woff + w) * 65536;
  const _Float16* Bb = Xn + (size_t)b * BHN;
  const int o0 = blockIdx.y * 128;
  const int bn0 = blockIdx.x * 128;

  __shared__ __align__(16) _Float16 Ah[4096];  // [128][32]
  __shared__ __align__(16) _Float16 Bh[4096];  // [128][32]

  const int tid = threadIdx.x;
  const int wave = tid >> 6;
  const int lane = tid & 63;
  const int lg = lane >> 4, ll = lane & 15;
  const int wm = wave >> 1, wn = wave & 1;
  const int r0 = tid >> 2, c4 = tid & 3;

  f32x4 acc[4][4];
#pragma unroll
  for (int mi = 0; mi < 4; ++mi)
#pragma unroll
    for (int ni = 0; ni < 4; ++ni) acc[mi][ni] = (f32x4){0.f, 0.f, 0.f, 0.f};

  for (int k0 = 0; k0 < 256; k0 += 32) {
    gl_lds16(Wb + (size_t)(o0 + r0) * 256 + k0 + c4 * 8, &Ah[wave * 512]);
    gl_lds16(Wb + (size_t)(o0 + 64 + r0) * 256 + k0 + c4 * 8,
             &Ah[2048 + wave * 512]);
    gl_lds16(Bb + (size_t)(bn0 + r0) * 256 + k0 + c4 * 8, &Bh[wave * 512]);
    gl_lds16(Bb + (size_t)(bn0 + 64 + r0) * 256 + k0 + c4 * 8,
             &Bh[2048 + wave * 512]);
    __syncthreads();
    half8 af[4], bf[4];
#pragma unroll
    for (int mi = 0; mi < 4; ++mi)
      af[mi] = *(const half8*)&Ah[(wm * 64 + mi * 16 + ll) * 32 + lg * 8];
#pragma unroll
    for (int ni = 0; ni < 4; ++ni)
      bf[ni] = *(const half8*)&Bh[(wn * 64 + ni * 16 + ll) * 32 + lg * 8];
#pragma unroll
    for (int mi = 0; mi < 4; ++mi)
#pragma unroll
      for (int ni = 0; ni < 4; ++ni)
        acc[mi][ni] = __builtin_amdgcn_mfma_f32_16x16x32_f16(
            af[mi], bf[ni], acc[mi][ni], 0, 0, 0);
    __syncthreads();
  }

#pragma unroll
  for (int mi = 0; mi < 4; ++mi) {
#pragma unroll
    for (int ni = 0; ni < 4; ++ni) {
      int o = o0 + wm * 64 + mi * 16 + lg * 4;   // channel (4 consecutive via r)
      int mcol = bn0 + wn * 64 + ni * 16 + ll;   // dd*1024 + token
      if constexpr (MODE == 1) {
        float* Ofb = Of + (size_t)b * BHN;
#pragma unroll
        for (int r = 0; r < 4; ++r)
          Ofb[(size_t)(o + r) * 3072 + mcol] = acc[mi][ni][r];
      } else {
        const int h = o >> 5, i = o & 31;
        const int dd = mcol >> 10, tok = mcol & 1023;
        const size_t bh8 = (size_t)(b * 8 + h);
        if (w == 2) {
          // Vp[bh][t][kt][dt=dd][lq=i(+r)][hi2][e]
          int tt = tok >> 6, kk = tok & 63;
          int kt = kk >> 4, hi2 = (kk >> 3) & 1, e = kk & 7;
          size_t base = ((((bh8 * 16 + tt) * 4 + kt) * 3 + dd) * 512) +
                        (size_t)i * 16 + hi2 * 8 + e;
#pragma unroll
          for (int r = 0; r < 4; ++r)
            O2[base + r * 16] = (_Float16)acc[mi][ni][r];
        } else {
          int dperm = dd * 32 + i;
          int pp = dperm >> 3, j0 = i & 7;
          int ks = pp >> 1, hif = pp & 1;
          float qs = (w == 0) ? SCL2 : 1.0f;
          _Float16 t4[4];
#pragma unroll
          for (int r = 0; r < 4; ++r) t4[r] = (_Float16)(acc[mi][ni][r] * qs);
          size_t idx;
          if (w == 0) {
            // Qp[bh][qt32][ks][ql][hi][j]
            idx = ((bh8 * 32 + (tok >> 5)) * 6 + ks) * 512 +
                  (size_t)(tok & 31) * 16 + hif * 8 + j0;
            *(uint2*)&O0[idx] = *(uint2*)t4;
          } else {
            // Kp[bh][t][ks][kk][hi][j]
            idx = ((bh8 * 16 + (tok >> 6)) * 6 + ks) * 1024 +
                  (size_t)(tok & 63) * 16 + hif * 8 + j0;
            *(uint2*)&O1[idx] = *(uint2*)t4;
          }
        }
      }
    }
  }
}

// ---------------------------------------------------------------------------
// Flash attention, 32x32 swapped-QK^T — LDS-free, barrier-free, packed
// fragment-major q/k/v (every fragment load = 64 lanes x 16B contiguous).
// ILP restructure: softmax packs ALL 16 pf words first (frees s), then PV
// runs as one unbroken 12-MFMA cluster; t-loop unrolled x2 so QK(t+1) can
// interleave with PV(t). Softmax in exp2 domain, defer-max THR=12.
// C/D map (HW-verified): col=lane&31, row=(r&3)+8*(r>>2)+4*(lane>>5).
// ---------------------------------------------------------------------------
__global__ __launch_bounds__(256, 2) void attn_kernel(
    const _Float16* __restrict__ Qp, const _Float16* __restrict__ Kp,
    const _Float16* __restrict__ Vp,
    const unsigned long long* __restrict__ mbits,
    _Float16* __restrict__ yT) {
  const int gid = blockIdx.x;
  const int bh = gid & 63;   // XCD = gid%8 = h: per-XCD K/V set L2-resident
  const int qt = gid >> 6;
  const int b = bh >> 3, h = bh & 7;
  const int n0 = qt * 128;

  const int tid = threadIdx.x;
  const int lane = tid & 63;
  const int wave = tid >> 6;
  const int hi = lane >> 5;
  const int lq = lane & 31;
  const int wq0 = wave * 32;

  const size_t bh8 = (size_t)(b * 8 + h);
  const int lo16 = lq * 16 + hi * 8;   // per-lane offset within a 2KB frag blk

  // ---- Q fragments (contiguous 1KB per frag) ----
  const _Float16* Qb = Qp + (bh8 * 32 + (qt * 4 + wave)) * 6 * 512 + lo16;
  half8 qf[6];
#pragma unroll
  for (int ks = 0; ks < 6; ++ks) qf[ks] = *(const half8*)(Qb + ks * 512);

  const _Float16* Kh = Kp + bh8 * 98304 + lo16;
  const _Float16* Vh = Vp + bh8 * 98304 + lo16;

  half8 kf[6][2];
  auto loadK = [&](int t) {
    const _Float16* Kt = Kh + t * 6144;
#pragma unroll
    for (int ks = 0; ks < 6; ++ks) {
      kf[ks][0] = *(const half8*)(Kt + ks * 1024);
      kf[ks][1] = *(const half8*)(Kt + ks * 1024 + 512);
    }
  };
  loadK(0);

  float M = 0.f, Lh = 0.f;
  f32x16 yacc[3];
#pragma unroll
  for (int dt = 0; dt < 3; ++dt)
#pragma unroll
    for (int r = 0; r < 16; ++r) yacc[dt][r] = 0.f;

#pragma unroll 2
  for (int t = 0; t < 16; ++t) {
    // ---- V fragments for this tile (12 x 2KB-dense loads), issued early ----
    const _Float16* Vt = Vh + t * 6144;
    half8 vf[4][3];
#pragma unroll
    for (int kt = 0; kt < 4; ++kt)
#pragma unroll
      for (int dt = 0; dt < 3; ++dt)
        vf[kt][dt] = *(const half8*)(Vt + (kt * 3 + dt) * 512);

    const unsigned long long m64 = mbits[b * 16 + t];

    // ---- S = K.Q^T (swapped): rows=keys, cols=q ----
    f32x16 s[2];
#pragma unroll
    for (int r = 0; r < 16; ++r) { s[0][r] = 0.f; s[1][r] = 0.f; }
    __builtin_amdgcn_s_setprio(1);
#pragma unroll
    for (int ks = 0; ks < 6; ++ks) {
      s[0] = __builtin_amdgcn_mfma_f32_32x32x16_f16(kf[ks][0], qf[ks], s[0],
                                                    0, 0, 0);
      s[1] = __builtin_amdgcn_mfma_f32_32x32x16_f16(kf[ks][1], qf[ks], s[1],
                                                    0, 0, 0);
    }
    __builtin_amdgcn_s_setprio(0);

    // ---- K reload for next tile (WAR on kf; covered by softmax+PV) ----
    if (t + 1 < 16) loadK(t + 1);

    // ---- mask + local max ----
    float mx = -1e30f;
#pragma unroll
    for (int nt = 0; nt < 2; ++nt) {
      unsigned wm = (unsigned)(m64 >> (nt * 32 + 4 * hi));
#pragma unroll
      for (int r = 0; r < 16; ++r) {
        float sv = s[nt][r];
        sv = ((wm >> ((r & 3) + 8 * (r >> 2))) & 1u) ? -1e30f : sv;
        s[nt][r] = sv;
        mx = fmaxf(mx, sv);
      }
    }
    // ---- deferred max (THR=12 in log2 domain: P <= 2^12) ----
    if (__any(mx > M + 12.f)) {
      float mx2 = fmaxf(mx, __shfl_xor(mx, 32));
      float newM = fmaxf(M, mx2);
      float corr = ex2(M - newM);
      M = newM;
      Lh *= corr;
#pragma unroll
      for (int dt = 0; dt < 3; ++dt)
#pragma unroll
        for (int r = 0; r < 16; ++r) yacc[dt][r] *= corr;
    }
    float psum = 0.f;
#pragma unroll
    for (int nt = 0; nt < 2; ++nt)
#pragma unroll
      for (int r = 0; r < 16; ++r) {
        float p = ex2(s[nt][r] - M);
        s[nt][r] = p;
        psum += p;
      }
    Lh += psum;

    // ---- pack ALL pf words first (frees s before PV) ----
    unsigned pw[4][4];
#pragma unroll
    for (int nt = 0; nt < 2; ++nt)
#pragma unroll
      for (int hf = 0; hf < 2; ++hf) {
        const int bs = hf * 8;
        unsigned A0 = pkh(s[nt][bs + 0], s[nt][bs + 1]);
        unsigned A1 = pkh(s[nt][bs + 2], s[nt][bs + 3]);
        unsigned B0 = pkh(s[nt][bs + 4], s[nt][bs + 5]);
        unsigned B1 = pkh(s[nt][bs + 6], s[nt][bs + 7]);
        plswap(A0, B0);
        plswap(A1, B1);
        pw[nt * 2 + hf][0] = A0;
        pw[nt * 2 + hf][1] = A1;
        pw[nt * 2 + hf][2] = B0;
        pw[nt * 2 + hf][3] = B1;
      }

    // ---- PV: one unbroken 12-MFMA cluster ----
    __builtin_amdgcn_s_setprio(1);
#pragma unroll
    for (int kt = 0; kt < 4; ++kt) {
      PF pf;
      pf.u[0] = pw[kt][0];
      pf.u[1] = pw[kt][1];
      pf.u[2] = pw[kt][2];
      pf.u[3] = pw[kt][3];
#pragma unroll
      for (int dt = 0; dt < 3; ++dt)
        yacc[dt] = __builtin_amdgcn_mfma_f32_32x32x16_f16(
            vf[kt][dt], pf.v, yacc[dt], 0, 0, 0);
    }
    __builtin_amdgcn_s_setprio(0);
  }

  // ---- epilogue: direct n-major stores ----
  float L = Lh + __shfl_xor(Lh, 32);
  float inv = (L > 0.f) ? 1.f / L : 0.f;
  _Float16* yb = yT + (size_t)b * BHN;
#pragma unroll
  for (int dt = 0; dt < 3; ++dt) {
    _Float16* rowp =
        yb + (size_t)(dt * 1024 + n0 + wq0 + lq) * 256 + h * 32 + hi * 4;
#pragma unroll
    for (int g = 0; g < 4; ++g) {
      _Float16 t4[4];
#pragma unroll
      for (int j = 0; j < 4; ++j)
        t4[j] = (_Float16)(yacc[dt][g * 4 + j] * inv);
      *(uint2*)(rowp + g * 8) = *(uint2*)t4;
    }
  }
}

// ---------------------------------------------------------------------------
extern "C" void kernel_launch(void* const* d_in, const int* in_sizes, int n_in,
                              void* d_out, int out_size, void* d_ws,
                              size_t ws_size, hipStream_t stream) {
  const float* x = (const float*)d_in[0];
  const float* Wq = (const float*)d_in[1];
  const float* Wk = (const float*)d_in[2];
  const float* Wv = (const float*)d_in[3];
  const float* Wp = (const float*)d_in[4];
  const unsigned* mask = (const unsigned*)d_in[5];
  float* out = (float*)d_out;

  _Float16* Wh = (_Float16*)d_ws;                   // 0.5 MB
  _Float16* XT = Wh + 4 * 65536;                    // 12.6 MB n-major
  _Float16* Qp = XT + (size_t)B_ * BHN;             // 12.6 MB packed frags
  _Float16* Kp = Qp + (size_t)B_ * BHN;             // 12.6 MB packed frags
  _Float16* Vp = Kp + (size_t)B_ * BHN;             // 12.6 MB packed frags
  _Float16* yT = Vp + (size_t)B_ * BHN;             // 12.6 MB n-major
  unsigned long long* mb = (unsigned long long*)(yT + (size_t)B_ * BHN);

  convw_kernel<<<128, 256, 0, stream>>>(Wq, Wk, Wv, Wp, Wh, mask, mb);
  convxt_kernel<<<dim3(48, 4, B_), 256, 0, stream>>>(x, XT);

  dim3 g1(24, 2, B_ * 3);
  mgemm_kernel<0><<<g1, 256, 0, stream>>>(Wh, 0, XT, Qp, Kp, Vp, nullptr, 3);

  attn_kernel<<<dim3(512), 256, 0, stream>>>(Qp, Kp, Vp, mb, yT);

  dim3 g3(24, 2, B_);
  mgemm_kernel<1><<<g3, 256, 0, stream>>>(Wh, 3, yT, nullptr, nullptr, nullptr,
                                          out, 1);
}